// Round 9
// baseline (96.288 us; speedup 1.0000x reference)
//
#include <hip/hip_runtime.h>

#define T 128
#define L2E 1.4426950408889634f   // log2(e)
#define LN2F 0.6931471805599453f  // ln(2)
#define SENT -3.0e37f

typedef _Float16 h2 __attribute__((ext_vector_type(2)));

// lane l <- lane l-1; lane 0 <- 0   (DPP wave_shr:1, bound_ctrl=0) -- verified r3-r8
__device__ __forceinline__ float shr1(float x) {
    return __int_as_float(__builtin_amdgcn_update_dpp(
        0, __float_as_int(x), 0x138, 0xF, 0xF, true));
}

template <int CTRL>
__device__ __forceinline__ float dppmax(float x) {
    float t = __int_as_float(__builtin_amdgcn_update_dpp(
        __float_as_int(x), __float_as_int(x), CTRL, 0xF, 0xF, false));
    return fmaxf(x, t);
}

__device__ __forceinline__ float dot2(h2 x, float ybits, float acc) {
    return __builtin_amdgcn_fdot2(x, __builtin_bit_cast(h2, ybits), acc, false);
}

struct Ent { float4 yo, ye; float so, se; };  // rows for one body: odd cell, even cell

__launch_bounds__(256)
__global__ void sdtw_kernel(const float* __restrict__ X,
                            const float* __restrict__ Y,
                            float* __restrict__ out) {
    // Paired-entry tables (one entry = both rows a body needs), stride 12 dw:
    //   EntA[k] (odd-q bodies):  rowO = r(2k),   rowE = r(2k+1)
    //   EntB[k] (even-q bodies): rowO = r(2k+1), rowE = r(2k+2)
    // r-index r holds y-row j = r-126 (valid j in [0,127], else sentinel E=0).
    // Entry dwords: [0..3] yO f16x8, [4..7] yE f16x8, [8] sqO, [9] sqE, [10,11] pad.
    __shared__ __align__(16) float lds[4 * 3180];   // (133+132)*12 dw per wave
    const int lane = threadIdx.x & 63;
    const int w    = threadIdx.x >> 6;
    const int pair = blockIdx.x * 4 + w;   // 512 blocks * 4 waves = 2048 pairs
    const int a = pair >> 4;               // X index
    const int b = pair & 15;               // Y index

    float* EA = lds + w * 3180;       // 133 entries
    float* EB = EA + 133 * 12;        // 132 entries

    // ---- stage entries ----
    {
        const float* ybase = Y + (size_t)b * T * 8;
        for (int idx = lane; idx < 265; idx += 64) {
            int isB = (idx >= 133);
            int k = isB ? idx - 133 : idx;
            int rO = 2 * k + isB;          // A: 2k, B: 2k+1
            int rE = rO + 1;
            float4 pkO, pkE;
            pkO.x=0.f; pkO.y=0.f; pkO.z=0.f; pkO.w=0.f;
            pkE.x=0.f; pkE.y=0.f; pkE.z=0.f; pkE.w=0.f;
            float sqO = SENT, sqE = SENT;
            const float c = 2.0f * L2E;
            int jO = rO - 126, jE = rE - 126;
            if (jO >= 0 && jO < T) {
                const float4* src = (const float4*)(ybase + jO * 8);
                float4 y0 = src[0], y1 = src[1];
                float s = y0.x*y0.x+y0.y*y0.y+y0.z*y0.z+y0.w*y0.w
                        + y1.x*y1.x+y1.y*y1.y+y1.z*y1.z+y1.w*y1.w;
                h2 a0={(_Float16)(c*y0.x),(_Float16)(c*y0.y)};
                h2 a1={(_Float16)(c*y0.z),(_Float16)(c*y0.w)};
                h2 a2={(_Float16)(c*y1.x),(_Float16)(c*y1.y)};
                h2 a3={(_Float16)(c*y1.z),(_Float16)(c*y1.w)};
                pkO.x=__builtin_bit_cast(float,a0); pkO.y=__builtin_bit_cast(float,a1);
                pkO.z=__builtin_bit_cast(float,a2); pkO.w=__builtin_bit_cast(float,a3);
                sqO = -L2E * s;
            }
            if (jE >= 0 && jE < T) {
                const float4* src = (const float4*)(ybase + jE * 8);
                float4 y0 = src[0], y1 = src[1];
                float s = y0.x*y0.x+y0.y*y0.y+y0.z*y0.z+y0.w*y0.w
                        + y1.x*y1.x+y1.y*y1.y+y1.z*y1.z+y1.w*y1.w;
                h2 a0={(_Float16)(c*y0.x),(_Float16)(c*y0.y)};
                h2 a1={(_Float16)(c*y0.z),(_Float16)(c*y0.w)};
                h2 a2={(_Float16)(c*y1.x),(_Float16)(c*y1.y)};
                h2 a3={(_Float16)(c*y1.z),(_Float16)(c*y1.w)};
                pkE.x=__builtin_bit_cast(float,a0); pkE.y=__builtin_bit_cast(float,a1);
                pkE.z=__builtin_bit_cast(float,a2); pkE.w=__builtin_bit_cast(float,a3);
                sqE = -L2E * s;
            }
            float* dst = (isB ? EB : EA) + k * 12;
            *(float4*)dst       = pkO;
            *(float4*)(dst + 4) = pkE;
            float2 sq2; sq2.x = sqO; sq2.y = sqE;
            *(float2*)(dst + 8) = sq2;
        }
    }

    // ---- X rows 2l (even cell) and 2l+1 (odd cell), f16 pairs ----
    h2 xe0, xe1, xe2, xe3, xo0, xo1, xo2, xo3;
    float lsxe, lsxo;
    {
        const float* xb = X + ((size_t)a * T + 2 * lane) * 8;
        const float4* s0p = (const float4*)xb;
        float4 v0 = s0p[0], v1 = s0p[1], u0 = s0p[2], u1 = s0p[3];
        xe0 = h2{ (_Float16)v0.x, (_Float16)v0.y };
        xe1 = h2{ (_Float16)v0.z, (_Float16)v0.w };
        xe2 = h2{ (_Float16)v1.x, (_Float16)v1.y };
        xe3 = h2{ (_Float16)v1.z, (_Float16)v1.w };
        lsxe = -L2E * (v0.x*v0.x+v0.y*v0.y+v0.z*v0.z+v0.w*v0.w
                      +v1.x*v1.x+v1.y*v1.y+v1.z*v1.z+v1.w*v1.w);
        xo0 = h2{ (_Float16)u0.x, (_Float16)u0.y };
        xo1 = h2{ (_Float16)u0.z, (_Float16)u0.w };
        xo2 = h2{ (_Float16)u1.x, (_Float16)u1.y };
        xo3 = h2{ (_Float16)u1.z, (_Float16)u1.w };
        lsxo = -L2E * (u0.x*u0.x+u0.y*u0.y+u0.z*u0.z+u0.w*u0.w
                      +u1.x*u1.x+u1.y*u1.y+u1.z*u1.z+u1.w*u1.w);
    }

    __syncthreads();

#define FA(S, K) { const float* q_ = EA + min((K), 132) * 12;                 \
    S.yo = *(const float4*)q_; S.ye = *(const float4*)(q_ + 4);               \
    float2 sq_ = *(const float2*)(q_ + 8); S.so = sq_.x; S.se = sq_.y; }
#define FB(S, K) { const float* q_ = EB + min((K), 131) * 12;                 \
    S.yo = *(const float4*)q_; S.ye = *(const float4*)(q_ + 4);               \
    float2 sq_ = *(const float2*)(q_ + 8); S.so = sq_.x; S.se = sq_.y; }

    // ---- prime ring: bodies p=1..4 use EntA[63-l], EntB[63-l], EntA[64-l], EntB[64-l]
    Ent s1, s2, s3, s4;
    const int k0 = 63 - lane;
    FA(s1, k0); FB(s2, k0); FA(s3, k0 + 1); FB(s4, k0 + 1);
    int kA = k0 + 2, kB = k0 + 2;   // fetch targets (bodies p+4)

    // ---- p = 0: even cell (0,0) on lane 0 (row 126-2l = s1.yo) ----
    float fe0 = 0.f, fo0 = 0.f, fo1 = 0.f, fe1;
    float sPrev = 0.f;
    int off = 90;
    {
        float acc = dot2(xe3, s1.yo.w, dot2(xe2, s1.yo.z,
                    dot2(xe1, s1.yo.y, dot2(xe0, s1.yo.x, lsxe + s1.so))));
        fe1 = __builtin_amdgcn_exp2f(acc) * 0x1p90f;
    }

    // BODY: PE1/PO1 = p-1 state, PE2/PO2 = p-2 state (overwritten).
#define BODY(PE1, PE2, PO1, PO2, S) {                                         \
    float ae = dot2(xe3, S.ye.w, dot2(xe2, S.ye.z,                            \
               dot2(xe1, S.ye.y, dot2(xe0, S.ye.x, lsxe + S.se))));           \
    float ao = dot2(xo3, S.yo.w, dot2(xo2, S.yo.z,                            \
               dot2(xo1, S.yo.y, dot2(xo0, S.yo.x, lsxo + S.so))));           \
    float Ee = __builtin_amdgcn_exp2f(ae);                                    \
    float Eo = __builtin_amdgcn_exp2f(ao);                                    \
    float sB = shr1(PO1);                                                     \
    float Se = Ee * ((sPrev + sB) + PE1);                                     \
    float So = Eo * ((PE2 + PE1) + PO1);                                      \
    sPrev = sB;                                                               \
    PE2 = Se; PO2 = So;                                                       \
}

#define RENORM() {                                                            \
    float mx = fmaxf(fmaxf(fe0, fe1), fmaxf(fo0, fo1));                       \
    mx = dppmax<0x111>(mx);                                                   \
    mx = dppmax<0x112>(mx);                                                   \
    mx = dppmax<0x114>(mx);                                                   \
    mx = dppmax<0x118>(mx);                                                   \
    int r0_ = __builtin_amdgcn_readlane(__float_as_int(mx), 15);              \
    int r1_ = __builtin_amdgcn_readlane(__float_as_int(mx), 31);              \
    int r2_ = __builtin_amdgcn_readlane(__float_as_int(mx), 47);              \
    int r3_ = __builtin_amdgcn_readlane(__float_as_int(mx), 63);              \
    int mb = max(max(r0_, r1_), max(r2_, r3_));                               \
    int e = ((mb >> 23) & 0xff) - 217;   /* renorm max to 2^90 */             \
    fe0 = ldexpf(fe0, -e); fe1 = ldexpf(fe1, -e);                             \
    fo0 = ldexpf(fo0, -e); fo1 = ldexpf(fo1, -e);                             \
    sPrev = ldexpf(sPrev, -e);                                                \
    off -= e;                                                                 \
}

    // ---- main: 31 groups of 8 bodies (p = 1..248), renorm per group ----
    for (int g = 0; g < 31; ++g) {
        BODY(fe1, fe0, fo1, fo0, s1); FA(s1, kA);       // p=8g+1, fetch p+4
        BODY(fe0, fe1, fo0, fo1, s2); FB(s2, kB);
        BODY(fe1, fe0, fo1, fo0, s3); FA(s3, kA + 1);
        BODY(fe0, fe1, fo0, fo1, s4); FB(s4, kB + 1);
        BODY(fe1, fe0, fo1, fo0, s1); FA(s1, kA + 2);
        BODY(fe0, fe1, fo0, fo1, s2); FB(s2, kB + 2);
        BODY(fe1, fe0, fo1, fo0, s3); FA(s3, kA + 3);
        BODY(fe0, fe1, fo0, fo1, s4); FB(s4, kB + 3);
        RENORM();
        kA += 4; kB += 4;
    }

    // ---- tail: p = 249..254 ----
    BODY(fe1, fe0, fo1, fo0, s1); FA(s1, kA);   // p=249, fetch for 253
    BODY(fe0, fe1, fo0, fo1, s2); FB(s2, kB);   // p=250, fetch for 254
    BODY(fe1, fe0, fo1, fo0, s3);               // p=251
    BODY(fe0, fe1, fo0, fo1, s4);               // p=252
    BODY(fe1, fe0, fo1, fo0, s1);               // p=253
    BODY(fe0, fe1, fo0, fo1, s2);               // p=254 -> new So in fo1

    // final cell (127,127) = odd row of lane 63: R = (off - log2(S)) * ln2
    if (lane == 63)
        out[pair] = ((float)off - __builtin_amdgcn_logf(fo1)) * LN2F;
}

extern "C" void kernel_launch(void* const* d_in, const int* in_sizes, int n_in,
                              void* d_out, int out_size, void* d_ws, size_t ws_size,
                              hipStream_t stream) {
    const float* X = (const float*)d_in[0];   // (128,128,8) f32
    const float* Y = (const float*)d_in[1];   // (16,128,8) f32
    float* out = (float*)d_out;               // (128,16) f32
    sdtw_kernel<<<512, 256, 0, stream>>>(X, Y, out);
}